// Round 4
// baseline (207.155 us; speedup 1.0000x reference)
//
#include <hip/hip_runtime.h>

// Problem constants
#define VV 50000
#define EE 512       // embedding dim (= GEMM K per half)
#define SS 1024      // conv filters (= GEMM N)
#define BB 64
#define LL 256
#define NTOK (BB*LL)         // 16384 token rows (GEMM M)
#define XROWS_PAD (NTOK + 8) // padded rows so last-tile staging never faults

// MX scales: X quantized as x*2^6, W as w*2^5; HW dequant via E8M0 block scales.
// E8M0 byte = 127 + log2(scale): 2^-6 -> 121 (0x79), 2^-5 -> 122 (0x7A).
#define SCALE_A 0x79797979
#define SCALE_B 0x7A7A7A7A

typedef __attribute__((ext_vector_type(8))) int i32x8;
typedef __attribute__((ext_vector_type(4))) float f32x4;

static __device__ __forceinline__ void glds16(const void* g, void* l) {
    __builtin_amdgcn_global_load_lds(
        (const __attribute__((address_space(1))) unsigned int*)g,
        (__attribute__((address_space(3))) unsigned int*)l,
        16, 0, 0);
}

// pack 8 floats (scaled) -> 8 fp8 e4m3 bytes (2 dwords)
static __device__ __forceinline__ uint2 pack8_fp8(float4 v0, float4 v1, float s) {
    int r0 = __builtin_amdgcn_cvt_pk_fp8_f32(v0.x * s, v0.y * s, 0, 0);
    r0 = __builtin_amdgcn_cvt_pk_fp8_f32(v0.z * s, v0.w * s, r0, 1);
    int r1 = __builtin_amdgcn_cvt_pk_fp8_f32(v1.x * s, v1.y * s, 0, 0);
    r1 = __builtin_amdgcn_cvt_pk_fp8_f32(v1.z * s, v1.w * s, r1, 1);
    uint2 o; o.x = (unsigned)r0; o.y = (unsigned)r1; return o;
}

// load one 32-byte A/B fragment (8 dwords) from two swizzled 16B chunks
static __device__ __forceinline__ i32x8 ldfrag(const unsigned char* rowbase, int c0, int c1) {
    const uint4 lo = *(const uint4*)(rowbase + c0 * 16);
    const uint4 hi = *(const uint4*)(rowbase + c1 * 16);
    i32x8 f;
    f[0] = lo.x; f[1] = lo.y; f[2] = lo.z; f[3] = lo.w;
    f[4] = hi.x; f[5] = hi.y; f[6] = hi.z; f[7] = hi.w;
    return f;
}

// Kernel 1: gather embedding rows by token index, fp32 -> fp8 e4m3 (x 2^6).
// grid = NTOK blocks x 64 threads; each thread converts 8 elements.
__global__ void gather_fp8_kernel(const int* __restrict__ inputs,
                                  const float* __restrict__ emb,
                                  unsigned char* __restrict__ Xq) {
    const int t = blockIdx.x;
    const int idx = inputs[t];
    const int lane = threadIdx.x;
    const float4 v0 = *(const float4*)(emb + (size_t)idx * EE + lane * 8);
    const float4 v1 = *(const float4*)(emb + (size_t)idx * EE + lane * 8 + 4);
    *(uint2*)(Xq + (size_t)t * EE + lane * 8) = pack8_fp8(v0, v1, 64.0f);
}

// Kernel 2: Wc fp32 -> fp8 (x 2^5), layout preserved [S][2E]; + zero `pre`.
// grid = 512 blocks x 256 threads x 8 elems = 1M elements.
__global__ void wc_fp8_kernel(const float* __restrict__ Wc,
                              unsigned char* __restrict__ Wq,
                              unsigned int* __restrict__ pre) {
    const int i = (blockIdx.x * 256 + threadIdx.x) * 8;
    const float4 v0 = *(const float4*)(Wc + i);
    const float4 v1 = *(const float4*)(Wc + i + 4);
    *(uint2*)(Wq + i) = pack8_fp8(v0, v1, 32.0f);
    if (blockIdx.x < BB) {  // zero pool buffer (encodes -inf): 64 x 1024 words
        uint4 z = {0u, 0u, 0u, 0u};
        *(uint4*)(pre + blockIdx.x * SS + threadIdx.x * 4) = z;
    }
}

// Kernel 3: fused dual-half MX-fp8 GEMM + sliding-window add + max-pool epilogue.
// conv[t,s] = X[t]·Wc[s,0:512] + X[t+1]·Wc[s,512:1024]  (valid when (t&255)!=255)
// MFMA: mfma_scale_f32_16x16x128_f8f6f4 (K=128/inst, E8M0 scales dequant the
// pre-scaled quantization). Tile TM=128 x TN=128, BK=128 bytes, 4 K-chunks.
// 4 waves 2x2, each 64x64, acc f32x4[4][4]. A-frag lane layout: m=lane&15,
// k = (lane>>4)*32 + j (one MX block per lane, contiguous).
// LDS: 8-row stripes, 16B chunks XOR-swizzled (chunk c of row r holds logical
// chunk c^(r&7)) -> conflict-free fragment reads; glds16 dest = stripe+lane*16.
__global__ __launch_bounds__(256, 3)
void conv_gemm_kernel(const unsigned char* __restrict__ Xq,
                      const unsigned char* __restrict__ Wq,
                      unsigned int* __restrict__ pre) {
    __shared__ unsigned char sX[136 * 128];  // rows 0..128 used (+1 for shift)
    __shared__ unsigned char sW[256 * 128];  // [h*128 + s_local][k]

    const int tid = threadIdx.x;
    const int w = tid >> 6;          // wave 0..3
    const int lane = tid & 63;
    const int wx = w & 1;            // n-half -> cols wx*64..+64
    const int wy = w >> 1;           // m-half -> rows wy*64..+64
    const int m0 = blockIdx.y * 128; // token-tile base (never crosses batch: 128|256)
    const int s0 = blockIdx.x * 128; // filter-tile base

    f32x4 acc[4][4];
    #pragma unroll
    for (int mt = 0; mt < 4; ++mt)
        #pragma unroll
        for (int nt = 0; nt < 4; ++nt)
            acc[mt][nt] = (f32x4){0.f, 0.f, 0.f, 0.f};

    const int lrow = lane >> 3;                    // row within 8-row stripe
    const int lcolsw = (((lane & 7) ^ lrow) * 16); // swizzled global col (bytes)
    const int quad = lane >> 4;
    const int l15 = lane & 15;
    const int swA  = l15 & 7;        // row&7 for unshifted fragment rows
    const int swA1 = (l15 + 1) & 7;  // row&7 for shifted (t+1) rows
    const int cb0 = 2 * quad;        // logical chunks cb0, cb0+1 (k = quad*32..+32)

    for (int kt = 0; kt < 4; ++kt) {
        const int k0 = kt * 128;
        // --- stage: X stripes 0..16 (17 calls), W stripes 0..31 ---
        #pragma unroll
        for (int i = 0; i < 4; ++i) {
            const int c = w + 4 * i;                       // 0..15
            glds16(Xq + (size_t)(m0 + c * 8 + lrow) * EE + k0 + lcolsw,
                   (char*)sX + c * 1024);
        }
        if (w == 0) {
            glds16(Xq + (size_t)(m0 + 128 + lrow) * EE + k0 + lcolsw,
                   (char*)sX + 16 * 1024);
        }
        #pragma unroll
        for (int i = 0; i < 8; ++i) {
            const int c = w + 4 * i;                       // 0..31
            const int wrow = c * 8 + lrow;                 // 0..255
            const int h = wrow >> 7, sl = wrow & 127;
            glds16(Wq + (size_t)(s0 + sl) * 1024 + h * 512 + k0 + lcolsw,
                   (char*)sW + c * 1024);
        }
        __syncthreads();

        // --- compute: 32 MFMAs (mg-split keeps VGPRs ~130) ---
        #pragma unroll
        for (int mg = 0; mg < 2; ++mg) {
            i32x8 aA[2], aB[2];
            #pragma unroll
            for (int j = 0; j < 2; ++j) {
                const int r = wy * 64 + (mg * 2 + j) * 16 + l15;
                aA[j] = ldfrag(sX + r * 128, cb0 ^ swA, (cb0 + 1) ^ swA);
                aB[j] = ldfrag(sX + (r + 1) * 128, cb0 ^ swA1, (cb0 + 1) ^ swA1);
            }
            #pragma unroll
            for (int nt = 0; nt < 4; ++nt) {
                const int rB = wx * 64 + nt * 16 + l15;
                const i32x8 b1 = ldfrag(sW + rB * 128, cb0 ^ swA, (cb0 + 1) ^ swA);
                const i32x8 b2 = ldfrag(sW + (128 + rB) * 128, cb0 ^ swA, (cb0 + 1) ^ swA);
                #pragma unroll
                for (int j = 0; j < 2; ++j) {
                    const int mt = mg * 2 + j;
                    acc[mt][nt] = __builtin_amdgcn_mfma_scale_f32_16x16x128_f8f6f4(
                        aA[j], b1, acc[mt][nt], 0, 0, 0, SCALE_A, 0, SCALE_B);
                    acc[mt][nt] = __builtin_amdgcn_mfma_scale_f32_16x16x128_f8f6f4(
                        aB[j], b2, acc[mt][nt], 0, 0, 0, SCALE_A, 0, SCALE_B);
                }
            }
        }
        __syncthreads();
    }

    // --- epilogue: mask l==255, column max, LDS-combine wy halves, atomicMax ---
    // C/D layout (16x16, shape-determined): col = lane&15, row = quad*4 + reg
    const int b = m0 >> 8;  // batch index
    float* smax = (float*)sX;  // reuse: [2][128]
    #pragma unroll
    for (int nt = 0; nt < 4; ++nt) {
        float cmax = -3.4e38f;
        #pragma unroll
        for (int mt = 0; mt < 4; ++mt) {
            const int rbase = m0 + wy * 64 + mt * 16 + quad * 4;
            #pragma unroll
            for (int r = 0; r < 4; ++r) {
                const float v = acc[mt][nt][r];
                const bool valid = (((rbase + r) & 255) != 255);
                cmax = valid ? fmaxf(cmax, v) : cmax;
            }
        }
        cmax = fmaxf(cmax, __shfl_xor(cmax, 16));
        cmax = fmaxf(cmax, __shfl_xor(cmax, 32));
        if (lane < 16) smax[wy * 128 + wx * 64 + nt * 16 + lane] = cmax;
    }
    __syncthreads();
    if (tid < 128) {
        const float m = fmaxf(smax[tid], smax[128 + tid]);
        const unsigned int u = __float_as_uint(m);
        const unsigned int e = (u & 0x80000000u) ? ~u : (u | 0x80000000u);
        atomicMax(pre + b * SS + s0 + tid, e);
    }
}

// Kernel 4: sigmoid(max + bc) -> h = sig·W1^T + b1 -> logits -> log_softmax.
__global__ __launch_bounds__(1024)
void classifier_kernel(const unsigned int* __restrict__ pre,
                       const float* __restrict__ bc,
                       const float* __restrict__ W1,
                       const float* __restrict__ b1,
                       const float* __restrict__ W2,
                       const float* __restrict__ b2,
                       float* __restrict__ out) {
    __shared__ float ssig[SS];
    __shared__ float sh[64];
    const int b = blockIdx.x;
    const int tid = threadIdx.x;
    {
        const unsigned int e = pre[b * SS + tid];
        const unsigned int u = (e & 0x80000000u) ? (e & 0x7FFFFFFFu) : ~e;
        const float x = __uint_as_float(u) + bc[tid];
        ssig[tid] = 1.0f / (1.0f + __expf(-x));
    }
    if (tid >= 50 && tid < 64) sh[tid] = 0.f;
    __syncthreads();
    const int w = tid >> 6, lane = tid & 63;
    const float4* sp = (const float4*)ssig;  // 256 float4
    for (int j = w; j < 50; j += 16) {
        const float4* wp = (const float4*)(W1 + j * SS);
        float p = 0.f;
        #pragma unroll
        for (int i = 0; i < 4; ++i) {
            const float4 a = sp[lane + i * 64];
            const float4 g = wp[lane + i * 64];
            p += a.x * g.x + a.y * g.y + a.z * g.z + a.w * g.w;
        }
        #pragma unroll
        for (int off = 32; off; off >>= 1) p += __shfl_xor(p, off);
        if (lane == 0) sh[j] = p + b1[j];
    }
    __syncthreads();
    if (w == 0) {
        const float hj = (lane < 50) ? sh[lane] : 0.f;
        const float w2a = (lane < 50) ? W2[lane] : 0.f;
        const float w2b = (lane < 50) ? W2[50 + lane] : 0.f;
        float l0 = hj * w2a, l1 = hj * w2b;
        #pragma unroll
        for (int off = 32; off; off >>= 1) {
            l0 += __shfl_xor(l0, off);
            l1 += __shfl_xor(l1, off);
        }
        if (lane == 0) {
            l0 += b2[0]; l1 += b2[1];
            const float m = fmaxf(l0, l1);
            const float lse = m + logf(expf(l0 - m) + expf(l1 - m));
            out[b * 2 + 0] = l0 - lse;
            out[b * 2 + 1] = l1 - lse;
        }
    }
}

extern "C" void kernel_launch(void* const* d_in, const int* in_sizes, int n_in,
                              void* d_out, int out_size, void* d_ws, size_t ws_size,
                              hipStream_t stream) {
    const int*   inputs = (const int*)  d_in[0];
    const float* emb    = (const float*)d_in[1];
    const float* Wc     = (const float*)d_in[2];
    const float* bc     = (const float*)d_in[3];
    const float* W1     = (const float*)d_in[4];
    const float* b1     = (const float*)d_in[5];
    const float* W2     = (const float*)d_in[6];
    const float* b2     = (const float*)d_in[7];
    float* out = (float*)d_out;

    // ws layout
    unsigned char* Xq = (unsigned char*)d_ws;                    // XROWS_PAD*512 fp8
    unsigned char* Wq = Xq + (size_t)XROWS_PAD * EE;             // 1024*1024 fp8
    unsigned int*  pre = (unsigned int*)(Wq + (size_t)SS * 1024); // 64*1024 u32

    gather_fp8_kernel<<<NTOK, 64, 0, stream>>>(inputs, emb, Xq);
    wc_fp8_kernel<<<512, 256, 0, stream>>>(Wc, Wq, pre);
    dim3 grid(SS / 128, NTOK / 128);  // (8, 128) = 1024 blocks
    conv_gemm_kernel<<<grid, 256, 0, stream>>>(Xq, Wq, pre);
    classifier_kernel<<<BB, 1024, 0, stream>>>(pre, bc, W1, b1, W2, b2, out);
}

// Round 5
// 203.438 us; speedup vs baseline: 1.0183x; 1.0183x over previous
//
#include <hip/hip_runtime.h>

// Problem constants
#define VV 50000
#define EE 512       // embedding dim (= GEMM K per half; also BYTES/row in fp8)
#define SS 1024      // conv filters (= GEMM N)
#define BB 64
#define LL 256
#define NTOK (BB*LL)         // 16384 token rows (GEMM M)
#define XROWS_PAD (NTOK + 8) // padded rows so last-tile staging never faults

// MX scales: X quantized as x*2^6, W as w*2^5; HW dequant via E8M0 block scales.
// E8M0 byte = 127 + log2(scale): 2^-6 -> 121 (0x79), 2^-5 -> 122 (0x7A).
#define SCALE_A 0x79797979
#define SCALE_B 0x7A7A7A7A

typedef __attribute__((ext_vector_type(8))) int i32x8;
typedef __attribute__((ext_vector_type(4))) float f32x4;

static __device__ __forceinline__ void glds16(const void* g, void* l) {
    __builtin_amdgcn_global_load_lds(
        (const __attribute__((address_space(1))) unsigned int*)g,
        (__attribute__((address_space(3))) unsigned int*)l,
        16, 0, 0);
}

// pack 8 floats (scaled) -> 8 fp8 e4m3 bytes (2 dwords)
static __device__ __forceinline__ uint2 pack8_fp8(float4 v0, float4 v1, float s) {
    int r0 = __builtin_amdgcn_cvt_pk_fp8_f32(v0.x * s, v0.y * s, 0, 0);
    r0 = __builtin_amdgcn_cvt_pk_fp8_f32(v0.z * s, v0.w * s, r0, 1);
    int r1 = __builtin_amdgcn_cvt_pk_fp8_f32(v1.x * s, v1.y * s, 0, 0);
    r1 = __builtin_amdgcn_cvt_pk_fp8_f32(v1.z * s, v1.w * s, r1, 1);
    uint2 o; o.x = (unsigned)r0; o.y = (unsigned)r1; return o;
}

// load one 32-byte A/B fragment (8 dwords) from two swizzled 16B chunks
static __device__ __forceinline__ i32x8 ldfrag(const unsigned char* rowbase, int c0, int c1) {
    const uint4 lo = *(const uint4*)(rowbase + c0 * 16);
    const uint4 hi = *(const uint4*)(rowbase + c1 * 16);
    i32x8 f;
    f[0] = lo.x; f[1] = lo.y; f[2] = lo.z; f[3] = lo.w;
    f[4] = hi.x; f[5] = hi.y; f[6] = hi.z; f[7] = hi.w;
    return f;
}

// Kernel 1 (merged prep): blocks 0..4095   -> embedding gather, fp32->fp8 (x2^6),
//                         blocks 4096..4607 -> Wc fp32->fp8 (x2^5) + zero `pre`.
// Gather: 4 tokens/block (64 lanes per token, 8 elems/lane).
__global__ __launch_bounds__(256)
void prep_kernel(const int* __restrict__ inputs,
                 const float* __restrict__ emb,
                 const float* __restrict__ Wc,
                 unsigned char* __restrict__ Xq,
                 unsigned char* __restrict__ Wq,
                 unsigned int* __restrict__ pre) {
    const int tid = threadIdx.x;
    if (blockIdx.x < 4096) {
        const int t = blockIdx.x * 4 + (tid >> 6);
        const int lane = tid & 63;
        const int idx = inputs[t];
        const float* src = emb + (size_t)idx * EE + lane * 8;
        const float4 v0 = *(const float4*)src;
        const float4 v1 = *(const float4*)(src + 4);
        *(uint2*)(Xq + (size_t)t * EE + lane * 8) = pack8_fp8(v0, v1, 64.0f);
    } else {
        const int bb = blockIdx.x - 4096;   // 0..511
        const int i = (bb * 256 + tid) * 8;
        const float4 v0 = *(const float4*)(Wc + i);
        const float4 v1 = *(const float4*)(Wc + i + 4);
        *(uint2*)(Wq + i) = pack8_fp8(v0, v1, 32.0f);
        if (bb < BB) {  // zero pool buffer (0 encodes -inf): 64 x 1024 words
            uint4 z = {0u, 0u, 0u, 0u};
            *(uint4*)(pre + bb * SS + tid * 4) = z;
        }
    }
}

// Kernel 2: fused dual-half MX-fp8 GEMM + sliding-window add + max-pool epilogue.
// conv[t,s] = X[t]·Wc[s,0:512] + X[t+1]·Wc[s,512:1024]  (valid when (t&255)!=255)
// MFMA: mfma_scale_f32_16x16x128_f8f6f4. Tile TM=128 x TN=128, BK=128 B, 4 kt.
// 4 waves 2x2, each 64x64, acc f32x4[4][4].
// Inner structure: all 8 A-fragments preloaded once per kt (kt-invariant LDS
// addresses; mt/nt offsets fold into ds_read immediates), then nt-outer with
// b1/b2 loaded ONCE each -> 32 ds_read_b128 per kt (was 48 with mg re-loads).
// A-frag lane layout: m=lane&15, k=(lane>>4)*32 + j (one MX block/lane).
// LDS: 8-row stripes, 16B chunks XOR-swizzled (phys chunk c of row r holds
// logical chunk c^(r&7)) -> uniform 8 words/bank, conflict-free.
__global__ __launch_bounds__(256, 3)
void conv_gemm_kernel(const unsigned char* __restrict__ Xq,
                      const unsigned char* __restrict__ Wq,
                      unsigned int* __restrict__ pre) {
    __shared__ unsigned char sX[136 * 128];  // rows 0..128 used (+1 for shift)
    __shared__ unsigned char sW[256 * 128];  // [h*128 + s_local][k]

    const int tid = threadIdx.x;
    const int w = tid >> 6;          // wave 0..3
    const int lane = tid & 63;
    const int wx = w & 1;            // n-half -> cols wx*64..+64
    const int wy = w >> 1;           // m-half -> rows wy*64..+64
    const int m0 = blockIdx.y * 128; // token-tile base (never crosses batch: 128|256)
    const int s0 = blockIdx.x * 128; // filter-tile base

    f32x4 acc[4][4];
    #pragma unroll
    for (int mt = 0; mt < 4; ++mt)
        #pragma unroll
        for (int nt = 0; nt < 4; ++nt)
            acc[mt][nt] = (f32x4){0.f, 0.f, 0.f, 0.f};

    const int lrow = lane >> 3;                    // row within 8-row stripe
    const int lcolsw = (((lane & 7) ^ lrow) * 16); // swizzled global col (bytes)
    const int quad = lane >> 4;
    const int l15 = lane & 15;
    const int swA  = l15 & 7;        // row&7 for unshifted fragment rows
    const int swA1 = (l15 + 1) & 7;  // row&7 for shifted (t+1) rows
    const int cb0 = 2 * quad;        // logical chunks cb0, cb0+1 (k = quad*32..+32)

    // kt-invariant fragment base pointers (chunk XORs are lane constants)
    const unsigned char* pA  = sX + (wy * 64 + l15) * 128;
    const unsigned char* pA1 = sX + (wy * 64 + l15 + 1) * 128;
    const unsigned char* pB1 = sW + (wx * 64 + l15) * 128;
    const unsigned char* pB2 = sW + (128 + wx * 64 + l15) * 128;
    const int cA0 = cb0 ^ swA,  cA1 = (cb0 + 1) ^ swA;
    const int cS0 = cb0 ^ swA1, cS1 = (cb0 + 1) ^ swA1;

    for (int kt = 0; kt < 4; ++kt) {
        const int k0 = kt * 128;
        // --- stage: X stripes 0..16 (17 calls), W stripes 0..31 ---
        #pragma unroll
        for (int i = 0; i < 4; ++i) {
            const int c = w + 4 * i;                       // 0..15
            glds16(Xq + (size_t)(m0 + c * 8 + lrow) * EE + k0 + lcolsw,
                   (char*)sX + c * 1024);
        }
        if (w == 0) {
            glds16(Xq + (size_t)(m0 + 128 + lrow) * EE + k0 + lcolsw,
                   (char*)sX + 16 * 1024);
        }
        #pragma unroll
        for (int i = 0; i < 8; ++i) {
            const int c = w + 4 * i;                       // 0..31
            const int wrow = c * 8 + lrow;                 // 0..255
            const int h = wrow >> 7, sl = wrow & 127;
            glds16(Wq + (size_t)(s0 + sl) * 1024 + h * 512 + k0 + lcolsw,
                   (char*)sW + c * 1024);
        }
        __syncthreads();

        // --- compute: preload 8 A-frags, then nt-outer, 32 MFMAs ---
        i32x8 aA[4], aB[4];
        #pragma unroll
        for (int mt = 0; mt < 4; ++mt) {
            aA[mt] = ldfrag(pA  + mt * 2048, cA0, cA1);
            aB[mt] = ldfrag(pA1 + mt * 2048, cS0, cS1);
        }
        #pragma unroll
        for (int nt = 0; nt < 4; ++nt) {
            const i32x8 b1 = ldfrag(pB1 + nt * 2048, cA0, cA1);
            const i32x8 b2 = ldfrag(pB2 + nt * 2048, cA0, cA1);
            #pragma unroll
            for (int mt = 0; mt < 4; ++mt)
                acc[mt][nt] = __builtin_amdgcn_mfma_scale_f32_16x16x128_f8f6f4(
                    aA[mt], b1, acc[mt][nt], 0, 0, 0, SCALE_A, 0, SCALE_B);
            #pragma unroll
            for (int mt = 0; mt < 4; ++mt)
                acc[mt][nt] = __builtin_amdgcn_mfma_scale_f32_16x16x128_f8f6f4(
                    aB[mt], b2, acc[mt][nt], 0, 0, 0, SCALE_A, 0, SCALE_B);
        }
        __syncthreads();
    }

    // --- epilogue: mask l==255, column max, LDS-combine wy halves, atomicMax ---
    // C/D layout (16x16, shape-determined): col = lane&15, row = quad*4 + reg
    const int b = m0 >> 8;  // batch index
    float* smax = (float*)sX;  // reuse: [2][128]
    #pragma unroll
    for (int nt = 0; nt < 4; ++nt) {
        float cmax = -3.4e38f;
        #pragma unroll
        for (int mt = 0; mt < 4; ++mt) {
            const int rbase = m0 + wy * 64 + mt * 16 + quad * 4;
            #pragma unroll
            for (int r = 0; r < 4; ++r) {
                const float v = acc[mt][nt][r];
                const bool valid = (((rbase + r) & 255) != 255);
                cmax = valid ? fmaxf(cmax, v) : cmax;
            }
        }
        cmax = fmaxf(cmax, __shfl_xor(cmax, 16));
        cmax = fmaxf(cmax, __shfl_xor(cmax, 32));
        if (lane < 16) smax[wy * 128 + wx * 64 + nt * 16 + lane] = cmax;
    }
    __syncthreads();
    if (tid < 128) {
        const float m = fmaxf(smax[tid], smax[128 + tid]);
        const unsigned int u = __float_as_uint(m);
        const unsigned int e = (u & 0x80000000u) ? ~u : (u | 0x80000000u);
        atomicMax(pre + b * SS + s0 + tid, e);
    }
}

// Kernel 3: sigmoid(max + bc) -> h = sig·W1^T + b1 -> logits -> log_softmax.
__global__ __launch_bounds__(1024)
void classifier_kernel(const unsigned int* __restrict__ pre,
                       const float* __restrict__ bc,
                       const float* __restrict__ W1,
                       const float* __restrict__ b1,
                       const float* __restrict__ W2,
                       const float* __restrict__ b2,
                       float* __restrict__ out) {
    __shared__ float ssig[SS];
    __shared__ float sh[64];
    const int b = blockIdx.x;
    const int tid = threadIdx.x;
    {
        const unsigned int e = pre[b * SS + tid];
        const unsigned int u = (e & 0x80000000u) ? (e & 0x7FFFFFFFu) : ~e;
        const float x = __uint_as_float(u) + bc[tid];
        ssig[tid] = 1.0f / (1.0f + __expf(-x));
    }
    if (tid >= 50 && tid < 64) sh[tid] = 0.f;
    __syncthreads();
    const int w = tid >> 6, lane = tid & 63;
    const float4* sp = (const float4*)ssig;  // 256 float4
    for (int j = w; j < 50; j += 16) {
        const float4* wp = (const float4*)(W1 + j * SS);
        float p = 0.f;
        #pragma unroll
        for (int i = 0; i < 4; ++i) {
            const float4 a = sp[lane + i * 64];
            const float4 g = wp[lane + i * 64];
            p += a.x * g.x + a.y * g.y + a.z * g.z + a.w * g.w;
        }
        #pragma unroll
        for (int off = 32; off; off >>= 1) p += __shfl_xor(p, off);
        if (lane == 0) sh[j] = p + b1[j];
    }
    __syncthreads();
    if (w == 0) {
        const float hj = (lane < 50) ? sh[lane] : 0.f;
        const float w2a = (lane < 50) ? W2[lane] : 0.f;
        const float w2b = (lane < 50) ? W2[50 + lane] : 0.f;
        float l0 = hj * w2a, l1 = hj * w2b;
        #pragma unroll
        for (int off = 32; off; off >>= 1) {
            l0 += __shfl_xor(l0, off);
            l1 += __shfl_xor(l1, off);
        }
        if (lane == 0) {
            l0 += b2[0]; l1 += b2[1];
            const float m = fmaxf(l0, l1);
            const float lse = m + logf(expf(l0 - m) + expf(l1 - m));
            out[b * 2 + 0] = l0 - lse;
            out[b * 2 + 1] = l1 - lse;
        }
    }
}

extern "C" void kernel_launch(void* const* d_in, const int* in_sizes, int n_in,
                              void* d_out, int out_size, void* d_ws, size_t ws_size,
                              hipStream_t stream) {
    const int*   inputs = (const int*)  d_in[0];
    const float* emb    = (const float*)d_in[1];
    const float* Wc     = (const float*)d_in[2];
    const float* bc     = (const float*)d_in[3];
    const float* W1     = (const float*)d_in[4];
    const float* b1     = (const float*)d_in[5];
    const float* W2     = (const float*)d_in[6];
    const float* b2     = (const float*)d_in[7];
    float* out = (float*)d_out;

    // ws layout
    unsigned char* Xq = (unsigned char*)d_ws;                    // XROWS_PAD*512 fp8
    unsigned char* Wq = Xq + (size_t)XROWS_PAD * EE;             // 1024*1024 fp8
    unsigned int*  pre = (unsigned int*)(Wq + (size_t)SS * 1024); // 64*1024 u32

    prep_kernel<<<4608, 256, 0, stream>>>(inputs, emb, Wc, Xq, Wq, pre);
    dim3 grid(SS / 128, NTOK / 128);  // (8, 128) = 1024 blocks
    conv_gemm_kernel<<<grid, 256, 0, stream>>>(Xq, Wq, pre);
    classifier_kernel<<<BB, 1024, 0, stream>>>(pre, bc, W1, b1, W2, b2, out);
}

// Round 6
// 180.125 us; speedup vs baseline: 1.1501x; 1.1294x over previous
//
#include <hip/hip_runtime.h>

// Problem constants
#define VV 50000
#define EE 512       // embedding dim (= GEMM K per half; also BYTES/row in fp8)
#define SS 1024      // conv filters (= GEMM N)
#define BB 64
#define LL 256
#define NTOK (BB*LL)         // 16384 token rows (GEMM M)
#define XROWS_PAD (NTOK + 8) // padded rows so last-tile staging never faults

// MX scales: X quantized as x*2^6, W as w*2^5; HW dequant via E8M0 block scales.
// E8M0 byte = 127 + log2(scale): 2^-6 -> 121 (0x79), 2^-5 -> 122 (0x7A).
#define SCALE_A 0x79797979
#define SCALE_B 0x7A7A7A7A

typedef __attribute__((ext_vector_type(8))) int i32x8;
typedef __attribute__((ext_vector_type(16))) float f32x16;

static __device__ __forceinline__ void glds16(const void* g, void* l) {
    __builtin_amdgcn_global_load_lds(
        (const __attribute__((address_space(1))) unsigned int*)g,
        (__attribute__((address_space(3))) unsigned int*)l,
        16, 0, 0);
}

// pack 8 floats (scaled) -> 8 fp8 e4m3 bytes (2 dwords)
static __device__ __forceinline__ uint2 pack8_fp8(float4 v0, float4 v1, float s) {
    int r0 = __builtin_amdgcn_cvt_pk_fp8_f32(v0.x * s, v0.y * s, 0, 0);
    r0 = __builtin_amdgcn_cvt_pk_fp8_f32(v0.z * s, v0.w * s, r0, 1);
    int r1 = __builtin_amdgcn_cvt_pk_fp8_f32(v1.x * s, v1.y * s, 0, 0);
    r1 = __builtin_amdgcn_cvt_pk_fp8_f32(v1.z * s, v1.w * s, r1, 1);
    uint2 o; o.x = (unsigned)r0; o.y = (unsigned)r1; return o;
}

// load one 32-byte fragment (8 dwords) from two swizzled 16B chunks of one row
static __device__ __forceinline__ i32x8 ldfrag(const unsigned char* rowbase, int c0, int c1) {
    const uint4 lo = *(const uint4*)(rowbase + c0 * 16);
    const uint4 hi = *(const uint4*)(rowbase + c1 * 16);
    i32x8 f;
    f[0] = lo.x; f[1] = lo.y; f[2] = lo.z; f[3] = lo.w;
    f[4] = hi.x; f[5] = hi.y; f[6] = hi.z; f[7] = hi.w;
    return f;
}

// Kernel 1 (prep): blocks 0..4095   -> embedding gather, fp32->fp8 (x2^6)
//                  blocks 4096..4607 -> Wc fp32->fp8 (x2^5)
__global__ __launch_bounds__(256)
void prep_kernel(const int* __restrict__ inputs,
                 const float* __restrict__ emb,
                 const float* __restrict__ Wc,
                 unsigned char* __restrict__ Xq,
                 unsigned char* __restrict__ Wq) {
    const int tid = threadIdx.x;
    if (blockIdx.x < 4096) {
        const int t = blockIdx.x * 4 + (tid >> 6);
        const int lane = tid & 63;
        const int idx = inputs[t];
        const float* src = emb + (size_t)idx * EE + lane * 8;
        const float4 v0 = *(const float4*)src;
        const float4 v1 = *(const float4*)(src + 4);
        *(uint2*)(Xq + (size_t)t * EE + lane * 8) = pack8_fp8(v0, v1, 64.0f);
    } else {
        const int bb = blockIdx.x - 4096;   // 0..511
        const int i = (bb * 256 + tid) * 8;
        const float4 v0 = *(const float4*)(Wc + i);
        const float4 v1 = *(const float4*)(Wc + i + 4);
        *(uint2*)(Wq + i) = pack8_fp8(v0, v1, 32.0f);
    }
}

// Kernel 2: fused dual-half MX-fp8 GEMM + sliding-window add + max-pool.
// conv[t,s] = X[t]·Wc[s,0:512] + X[t+1]·Wc[s,512:1024]  (valid when (t&255)!=255)
// MFMA: mfma_scale_f32_32x32x64_f8f6f4 (K=64 = 2 MX blocks).
// Tile TM=256 (= ONE FULL BATCH ROW -> max-pool completes in-block, no atomics,
// no pre-init) x TN=128, BK=128 B, 4 kt. Grid 64x8 = 512 blocks = 2/CU exactly.
// 4 waves 2x2; wave tile 128 rows x 64 cols = 4 row-tiles x 2 col-tiles of
// 32x32, acc f32x16[4][2] (128 VGPR).
// Inner: preload 8 B-frags once per kt (64 VGPR), then rt-outer: 4 A-frags
// (unshifted + shifted rows, 2 k-steps) + 8 MFMAs -> 24 ds_read_b128 per kt
// per wave for 2.1M MACs (2.7x fewer LDS reads/MAC than the 16x16 version).
// A/B frag layout (32x32x64): m|n = lane&31, k = (lane>>5)*32 + j.
// LDS: 8-row stripes of 8 16B chunks, XOR swizzle (phys chunk c of row r holds
// logical c^(r&7)) -> conflict-free; glds16 dest = stripe + lane*16.
__global__ __launch_bounds__(256, 2)
void conv_gemm_kernel(const unsigned char* __restrict__ Xq,
                      const unsigned char* __restrict__ Wq,
                      float* __restrict__ pre) {
    __shared__ unsigned char sX[264 * 128];  // rows 0..256 used (+1 for shift)
    __shared__ unsigned char sW[256 * 128];  // [half*128 + s_local][k]

    const int tid = threadIdx.x;
    const int w = tid >> 6;          // wave 0..3
    const int lane = tid & 63;
    const int wx = w & 1;            // n-half -> cols wx*64..+64
    const int wy = w >> 1;           // m-half -> rows wy*128..+128
    const int b  = blockIdx.y;       // batch row; m0 = b*256
    const int m0 = b * 256;
    const int s0 = blockIdx.x * 128; // filter-tile base

    f32x16 acc[4][2];
    #pragma unroll
    for (int rt = 0; rt < 4; ++rt)
        #pragma unroll
        for (int nt = 0; nt < 2; ++nt)
            acc[rt][nt] = (f32x16)(0.f);

    const int lrow = lane >> 3;                    // row within 8-row stripe
    const int lcolsw = (((lane & 7) ^ lrow) * 16); // swizzled global col (bytes)
    const int l31 = lane & 31;
    const int lh  = lane >> 5;        // which 32-lane half (k-block select)
    const int sz0 = lane & 7;         // row&7 for unshifted rows
    const int sz1 = (l31 + 1) & 7;    // row&7 for shifted (t+1) rows

    // chunk indices (lane constants): k-step s uses logical chunks s*4+2*lh, +1
    const int cb0 = 2 * lh;          // s=0
    const int cb1 = 4 + 2 * lh;      // s=1

    // row base pointers (kt-invariant)
    const unsigned char* pA0 = sX + (wy * 128 + l31) * 128;      // unshifted
    const unsigned char* pA1 = pA0 + 128;                        // shifted (+1 row)
    const unsigned char* pB1 = sW + (wx * 64 + l31) * 128;       // Wc half 1
    const unsigned char* pB2 = pB1 + 128 * 128;                  // Wc half 2

    #pragma unroll 1
    for (int kt = 0; kt < 4; ++kt) {
        const int k0 = kt * 128;
        // --- stage: X stripes 0..32 (33 KB), W stripes 0..31 (32 KB) ---
        #pragma unroll
        for (int i = 0; i < 8; ++i) {
            const int st = w + 4 * i;                      // 0..31
            glds16(Xq + (size_t)(m0 + st * 8 + lrow) * EE + k0 + lcolsw,
                   (char*)sX + st * 1024);
            const int wrow = st * 8 + lrow;                // 0..255
            const int h = wrow >> 7, sl = wrow & 127;
            glds16(Wq + (size_t)(s0 + sl) * 1024 + h * 512 + k0 + lcolsw,
                   (char*)sW + st * 1024);
        }
        if (w == 0) {   // X rows 256..263 (only 256 used; global side padded)
            glds16(Xq + (size_t)(m0 + 256 + lrow) * EE + k0 + lcolsw,
                   (char*)sX + 32 * 1024);
        }
        __syncthreads();

        // --- compute: preload 8 B frags, then rt-outer (4 A frags + 8 MFMAs) ---
        i32x8 b1[2][2], b2[2][2];   // [nt][s]
        #pragma unroll
        for (int nt = 0; nt < 2; ++nt) {
            b1[nt][0] = ldfrag(pB1 + nt * 4096, cb0 ^ sz0, (cb0 + 1) ^ sz0);
            b1[nt][1] = ldfrag(pB1 + nt * 4096, cb1 ^ sz0, (cb1 + 1) ^ sz0);
            b2[nt][0] = ldfrag(pB2 + nt * 4096, cb0 ^ sz0, (cb0 + 1) ^ sz0);
            b2[nt][1] = ldfrag(pB2 + nt * 4096, cb1 ^ sz0, (cb1 + 1) ^ sz0);
        }
        #pragma unroll
        for (int rt = 0; rt < 4; ++rt) {
            i32x8 a0[2], a1[2];
            a0[0] = ldfrag(pA0 + rt * 4096, cb0 ^ sz0, (cb0 + 1) ^ sz0);
            a0[1] = ldfrag(pA0 + rt * 4096, cb1 ^ sz0, (cb1 + 1) ^ sz0);
            a1[0] = ldfrag(pA1 + rt * 4096, cb0 ^ sz1, (cb0 + 1) ^ sz1);
            a1[1] = ldfrag(pA1 + rt * 4096, cb1 ^ sz1, (cb1 + 1) ^ sz1);
            #pragma unroll
            for (int s = 0; s < 2; ++s)
                #pragma unroll
                for (int nt = 0; nt < 2; ++nt) {
                    acc[rt][nt] = __builtin_amdgcn_mfma_scale_f32_32x32x64_f8f6f4(
                        a0[s], b1[nt][s], acc[rt][nt], 0, 0, 0, SCALE_A, 0, SCALE_B);
                    acc[rt][nt] = __builtin_amdgcn_mfma_scale_f32_32x32x64_f8f6f4(
                        a1[s], b2[nt][s], acc[rt][nt], 0, 0, 0, SCALE_A, 0, SCALE_B);
                }
        }
        __syncthreads();
    }

    // --- epilogue: mask t_local==255, column max, combine wy halves, store ---
    // C/D layout (32x32): col = lane&31, row = (reg&3) + 8*(reg>>2) + 4*(lane>>5)
    float* smax = (float*)sX;  // reuse: [2][128]
    #pragma unroll
    for (int nt = 0; nt < 2; ++nt) {
        float cmax = -3.4e38f;
        #pragma unroll
        for (int rt = 0; rt < 4; ++rt) {
            #pragma unroll
            for (int reg = 0; reg < 16; ++reg) {
                const int row = (reg & 3) + 8 * (reg >> 2) + 4 * lh;
                const int tl = wy * 128 + rt * 32 + row;   // token within batch
                const float v = acc[rt][nt][reg];
                cmax = (tl != 255) ? fmaxf(cmax, v) : cmax;
            }
        }
        cmax = fmaxf(cmax, __shfl_xor(cmax, 32));
        if (lane < 32) smax[wy * 128 + wx * 64 + nt * 32 + lane] = cmax;
    }
    __syncthreads();
    if (tid < 128)  // max-pool complete for this (batch, filter) — direct store
        pre[b * SS + s0 + tid] = fmaxf(smax[tid], smax[128 + tid]);
}

// Kernel 3: sigmoid(max + bc) -> h = sig·W1^T + b1 -> logits -> log_softmax.
__global__ __launch_bounds__(1024)
void classifier_kernel(const float* __restrict__ pre,
                       const float* __restrict__ bc,
                       const float* __restrict__ W1,
                       const float* __restrict__ b1,
                       const float* __restrict__ W2,
                       const float* __restrict__ b2,
                       float* __restrict__ out) {
    __shared__ float ssig[SS];
    __shared__ float sh[64];
    const int b = blockIdx.x;
    const int tid = threadIdx.x;
    {
        const float x = pre[b * SS + tid] + bc[tid];
        ssig[tid] = 1.0f / (1.0f + __expf(-x));
    }
    if (tid >= 50 && tid < 64) sh[tid] = 0.f;
    __syncthreads();
    const int w = tid >> 6, lane = tid & 63;
    const float4* sp = (const float4*)ssig;  // 256 float4
    for (int j = w; j < 50; j += 16) {
        const float4* wp = (const float4*)(W1 + j * SS);
        float p = 0.f;
        #pragma unroll
        for (int i = 0; i < 4; ++i) {
            const float4 a = sp[lane + i * 64];
            const float4 g = wp[lane + i * 64];
            p += a.x * g.x + a.y * g.y + a.z * g.z + a.w * g.w;
        }
        #pragma unroll
        for (int off = 32; off; off >>= 1) p += __shfl_xor(p, off);
        if (lane == 0) sh[j] = p + b1[j];
    }
    __syncthreads();
    if (w == 0) {
        const float hj = (lane < 50) ? sh[lane] : 0.f;
        const float w2a = (lane < 50) ? W2[lane] : 0.f;
        const float w2b = (lane < 50) ? W2[50 + lane] : 0.f;
        float l0 = hj * w2a, l1 = hj * w2b;
        #pragma unroll
        for (int off = 32; off; off >>= 1) {
            l0 += __shfl_xor(l0, off);
            l1 += __shfl_xor(l1, off);
        }
        if (lane == 0) {
            l0 += b2[0]; l1 += b2[1];
            const float m = fmaxf(l0, l1);
            const float lse = m + logf(expf(l0 - m) + expf(l1 - m));
            out[b * 2 + 0] = l0 - lse;
            out[b * 2 + 1] = l1 - lse;
        }
    }
}

extern "C" void kernel_launch(void* const* d_in, const int* in_sizes, int n_in,
                              void* d_out, int out_size, void* d_ws, size_t ws_size,
                              hipStream_t stream) {
    const int*   inputs = (const int*)  d_in[0];
    const float* emb    = (const float*)d_in[1];
    const float* Wc     = (const float*)d_in[2];
    const float* bc     = (const float*)d_in[3];
    const float* W1     = (const float*)d_in[4];
    const float* b1     = (const float*)d_in[5];
    const float* W2     = (const float*)d_in[6];
    const float* b2     = (const float*)d_in[7];
    float* out = (float*)d_out;

    // ws layout
    unsigned char* Xq = (unsigned char*)d_ws;                    // XROWS_PAD*512 fp8
    unsigned char* Wq = Xq + (size_t)XROWS_PAD * EE;             // 1024*1024 fp8
    float*         pre = (float*)(Wq + (size_t)SS * 1024);       // 64*1024 f32

    prep_kernel<<<4608, 256, 0, stream>>>(inputs, emb, Wc, Xq, Wq);
    dim3 grid(SS / 128, NTOK / 256);  // (8, 64) = 512 blocks, 2/CU exactly
    conv_gemm_kernel<<<grid, 256, 0, stream>>>(Xq, Wq, pre);
    classifier_kernel<<<BB, 1024, 0, stream>>>(pre, bc, W1, b1, W2, b2, out);
}